// Round 3
// baseline (11842.959 us; speedup 1.0000x reference)
//
#include <hip/hip_runtime.h>
#include <hip/hip_bf16.h>

#define N_NODES 100000
#define N_EDGES 1600000
#define N_GRAPHS 1000
#define HID 64
#define GRP 10

// ---------- helpers ----------
__device__ __forceinline__ float bf1(unsigned short u){ union{unsigned int x; float f;} v; v.x = ((unsigned int)u)<<16; return v.f; }
__device__ __forceinline__ unsigned short f2bf(float f){
  union{float f; unsigned int i;} v; v.f = f;
  unsigned int r = v.i + 0x7FFFu + ((v.i >> 16) & 1u);
  return (unsigned short)(r >> 16);
}
__device__ __forceinline__ float eluf(float v){ return v > 0.f ? v : expm1f(v); }

// ---------- weight transpose (f32 -> f32) ----------
struct CvtEnt { const float* s; float* d; int rows; int cols; };
struct CvtArgs { CvtEnt e[16]; int cnt; };

__global__ __launch_bounds__(256) void k_convert(CvtArgs a){
  CvtEnt E = a.e[blockIdx.y];
  int n = E.rows * E.cols;
  for (int i = blockIdx.x*256 + threadIdx.x; i < n; i += gridDim.x*256){
    int r = i / E.cols, c = i % E.cols;
    E.d[(size_t)c*E.rows + r] = E.s[i];
  }
}

// ---------- CSR build ----------
__global__ __launch_bounds__(256) void k_deg(const int* __restrict__ dst, int* __restrict__ deg){
  int e = blockIdx.x*256 + threadIdx.x;
  if (e < N_EDGES) atomicAdd(deg + dst[e], 1);
}

__global__ __launch_bounds__(1024) void k_scan(const int* __restrict__ deg,
  int* __restrict__ offs, int* __restrict__ cursor)
{
  __shared__ int part[1024];
  int t = threadIdx.x;
  const int per = (N_NODES + 1023)/1024;
  int n0 = t*per, n1 = min(N_NODES, n0+per);
  int s = 0;
  for (int n=n0;n<n1;n++) s += deg[n];
  part[t] = s; __syncthreads();
  for (int o=1; o<1024; o<<=1){
    int v = (t>=o) ? part[t-o] : 0;
    __syncthreads();
    part[t] += v;
    __syncthreads();
  }
  int base = (t==0) ? 0 : part[t-1];
  for (int n=n0;n<n1;n++){ offs[n]=base; cursor[n]=base; base += deg[n]; }
  if (t==1023) offs[N_NODES] = part[1023];
}

__global__ __launch_bounds__(256) void k_fill(const int* __restrict__ src,
  const int* __restrict__ dst, int* __restrict__ cursor,
  int* __restrict__ csr_src, int* __restrict__ csr_eid)
{
  int e = blockIdx.x*256 + threadIdx.x;
  if (e >= N_EDGES) return;
  int d = dst[e];
  int pos = atomicAdd(cursor + d, 1);
  csr_src[pos] = src[e];
  csr_eid[pos] = e;
}

// graph offsets from sorted batch
__global__ __launch_bounds__(256) void k_goffs(const int* __restrict__ batch, int* __restrict__ goffs){
  int n = blockIdx.x*256 + threadIdx.x;
  if (n >= N_NODES) return;
  int b = batch[n];
  int bp = (n==0) ? -1 : batch[n-1];
  for (int g=bp+1; g<=b; g++) goffs[g] = n;
  if (n == N_NODES-1) for (int g=b+1; g<=N_GRAPHS; g++) goffs[g] = N_NODES;
}

// ---------- generic linear: out[n,0..63] = act(A[n,:] @ W + b), f32 ----------
template<int K, int RELU>
__global__ __launch_bounds__(256,4) void k_linear64(const float* __restrict__ Ap,
    const float* __restrict__ WT, const float* __restrict__ bias, float* __restrict__ Op, int N)
{
  int n = blockIdx.x*256 + threadIdx.x;
  if (n >= N) return;
  float a[K];
  const float4* p = (const float4*)(Ap + (size_t)n*K);
  #pragma unroll
  for (int i=0;i<K/4;i++){ float4 v=p[i]; a[4*i]=v.x; a[4*i+1]=v.y; a[4*i+2]=v.z; a[4*i+3]=v.w; }
  for (int c=0;c<64;c+=4){
    float s0 = bias[c+0], s1 = bias[c+1], s2 = bias[c+2], s3 = bias[c+3];
    const float* w = WT + (size_t)c*K;
    #pragma unroll
    for (int k=0;k<K;k++){
      float av = a[k];
      s0 = fmaf(av, w[k],     s0);
      s1 = fmaf(av, w[K+k],   s1);
      s2 = fmaf(av, w[2*K+k], s2);
      s3 = fmaf(av, w[3*K+k], s3);
    }
    if (RELU){ s0=fmaxf(s0,0.f); s1=fmaxf(s1,0.f); s2=fmaxf(s2,0.f); s3=fmaxf(s3,0.f); }
    float4 r; r.x=s0; r.y=s1; r.z=s2; r.w=s3;
    *(float4*)(Op + (size_t)n*64 + c) = r;
  }
}

// ---------- fused edge MLP: e_emb = (relu(edge_attr @ preE + eb)) @ We  -> bf16 ----------
__global__ __launch_bounds__(256,3) void k_edge_mlp(
  const float* __restrict__ EA, const float* __restrict__ WA /*[64][50]*/,
  const float* __restrict__ eb, const float* __restrict__ WB /*[64][64]*/,
  unsigned short* __restrict__ out)
{
  int e = blockIdx.x*256 + threadIdx.x;
  if (e >= N_EDGES) return;
  float a[50];
  const float2* p2 = (const float2*)(EA + (size_t)e*50);
  #pragma unroll
  for (int i=0;i<25;i++){ float2 v=p2[i]; a[2*i]=v.x; a[2*i+1]=v.y; }
  float t[64];
  for (int c=0;c<64;c+=4){
    float s0=eb[c], s1=eb[c+1], s2=eb[c+2], s3=eb[c+3];
    const float* w = WA + (size_t)c*50;
    #pragma unroll
    for (int k=0;k<50;k++){
      float av=a[k];
      s0=fmaf(av,w[k],s0);     s1=fmaf(av,w[50+k],s1);
      s2=fmaf(av,w[100+k],s2); s3=fmaf(av,w[150+k],s3);
    }
    t[c]=fmaxf(s0,0.f); t[c+1]=fmaxf(s1,0.f); t[c+2]=fmaxf(s2,0.f); t[c+3]=fmaxf(s3,0.f);
  }
  for (int c=0;c<64;c+=4){
    float s0=0.f,s1=0.f,s2=0.f,s3=0.f;
    const float* w = WB + (size_t)c*64;
    #pragma unroll
    for (int k=0;k<64;k++){
      float tv=t[k];
      s0=fmaf(tv,w[k],s0);     s1=fmaf(tv,w[64+k],s1);
      s2=fmaf(tv,w[128+k],s2); s3=fmaf(tv,w[192+k],s3);
    }
    uint2 uu;
    uu.x = ((unsigned int)f2bf(s1)<<16) | f2bf(s0);
    uu.y = ((unsigned int)f2bf(s3)<<16) | f2bf(s2);
    *(uint2*)(out + (size_t)e*64 + c) = uu;
  }
}

// ---------- fused GATv2 (CSR gather, wave per dst): logits -> softmax -> agg -> elu(+bias) ----------
__global__ __launch_bounds__(256) void k_gat_csr(
  const int* __restrict__ offs, const int* __restrict__ csr_src, const int* __restrict__ csr_eid,
  const float* __restrict__ xl, const float* __restrict__ xr,
  const unsigned short* __restrict__ emb, const float* __restrict__ att,
  const float* __restrict__ gatb,
  float* __restrict__ logits, float* __restrict__ hbuf)
{
  int lane = threadIdx.x & 63;
  int d = (blockIdx.x*256 + threadIdx.x) >> 6;
  if (d >= N_NODES) return;
  int off0 = offs[d], off1 = offs[d+1];
  float xr_d = xr[(size_t)d*64 + lane];
  float attv = att[lane];
  float m = -3.0e38f;
  for (int i = off0; i < off1; i++){
    int s = csr_src[i];
    int e = csr_eid[i];
    float v = xl[(size_t)s*64 + lane] + xr_d + bf1(emb[(size_t)e*64 + lane]);
    v = v > 0.f ? v : 0.01f*v;
    float p = v * attv;
    #pragma unroll
    for (int o=32;o;o>>=1) p += __shfl_xor(p,o,64);
    if (lane==0) logits[i] = p;
    m = fmaxf(m, p);
  }
  float sum = 0.f;
  for (int i0 = off0; i0 < off1; i0 += 64){
    int i = i0 + lane;
    if (i < off1) sum += __expf(logits[i]-m);
  }
  #pragma unroll
  for (int o=32;o;o>>=1) sum += __shfl_xor(sum,o,64);
  float inv = 1.f/(sum + 1e-16f);
  float acc = 0.f;
  for (int i = off0; i < off1; i++){
    float w = __expf(logits[i]-m);
    acc = fmaf(xl[(size_t)csr_src[i]*64 + lane], w, acc);
  }
  hbuf[(size_t)d*64 + lane] = eluf(acc*inv + gatb[lane]);
}

// ---------- fused GATv2 global readout (block per graph, contiguous node ranges) ----------
__global__ __launch_bounds__(256) void k_gat_graph(
  const int* __restrict__ goffs, const float* __restrict__ xl,
  const float* __restrict__ xr, const float* __restrict__ att, const float* __restrict__ gatb,
  float* __restrict__ logits, float* __restrict__ hbuf)
{
  int g = blockIdx.x;
  int lane = threadIdx.x & 63, wv = threadIdx.x >> 6;
  int n0 = goffs[g], n1 = goffs[g+1];
  __shared__ float red[4];
  __shared__ float accs[4][64];
  float xr_g = xr[(size_t)g*64 + lane];
  float attv = att[lane];
  float m = -3.0e38f;
  for (int n = n0 + wv; n < n1; n += 4){
    float v = xl[(size_t)n*64 + lane] + xr_g;
    v = v > 0.f ? v : 0.01f*v;
    float p = v * attv;
    #pragma unroll
    for (int o=32;o;o>>=1) p += __shfl_xor(p,o,64);
    if (lane==0) logits[n] = p;
    m = fmaxf(m, p);
  }
  if (lane==0) red[wv] = m;
  __syncthreads();
  m = fmaxf(fmaxf(red[0],red[1]), fmaxf(red[2],red[3]));
  __syncthreads();
  float sum = 0.f;
  for (int n = n0 + wv; n < n1; n += 4) sum += __expf(logits[n]-m);
  if (lane==0) red[wv] = sum;
  __syncthreads();
  sum = red[0]+red[1]+red[2]+red[3];
  float inv = 1.f/(sum + 1e-16f);
  float acc = 0.f;
  for (int n = n0 + wv; n < n1; n += 4){
    float w = __expf(logits[n]-m);
    acc = fmaf(xl[(size_t)n*64 + lane], w, acc);
  }
  accs[wv][lane] = acc;
  __syncthreads();
  if (wv==0){
    float a = accs[0][lane]+accs[1][lane]+accs[2][lane]+accs[3][lane];
    hbuf[(size_t)g*64 + lane] = eluf(a*inv + gatb[lane]);
  }
}

// ---------- GRU: x = relu(gru(h, x)) in-place ----------
__global__ __launch_bounds__(256,3) void k_gru(const float* __restrict__ hin, float* x,
  const float* __restrict__ Wih, const float* __restrict__ Whh,
  const float* __restrict__ bih, const float* __restrict__ bhh, int N)
{
  int n = blockIdx.x*256 + threadIdx.x;
  if (n >= N) return;
  float h[64], xv[64];
  const float4* pa = (const float4*)(hin + (size_t)n*64);
  const float4* px = (const float4*)(x   + (size_t)n*64);
  #pragma unroll
  for (int i=0;i<16;i++){
    float4 hh = pa[i]; float4 xx = px[i];
    h[4*i+0]=hh.x; h[4*i+1]=hh.y; h[4*i+2]=hh.z; h[4*i+3]=hh.w;
    xv[4*i+0]=xx.x; xv[4*i+1]=xx.y; xv[4*i+2]=xx.z; xv[4*i+3]=xx.w;
  }
  for (int c=0;c<64;c++){
    float ir=bih[c], iz=bih[64+c], in2=bih[128+c];
    float hr=bhh[c], hz=bhh[64+c], hn=bhh[128+c];
    const float* wi = Wih + (size_t)c*64;
    const float* wh = Whh + (size_t)c*64;
    #pragma unroll
    for (int k=0;k<64;k++){
      float hk = h[k], xk = xv[k];
      ir  = fmaf(hk, wi[k],      ir);
      iz  = fmaf(hk, wi[4096+k], iz);
      in2 = fmaf(hk, wi[8192+k], in2);
      hr  = fmaf(xk, wh[k],      hr);
      hz  = fmaf(xk, wh[4096+k], hz);
      hn  = fmaf(xk, wh[8192+k], hn);
    }
    float r = 1.f/(1.f + expf(-(ir+hr)));
    float z = 1.f/(1.f + expf(-(iz+hz)));
    float nn = tanhf(in2 + r*hn);
    float o = (1.f - z)*nn + z*xv[c];
    x[(size_t)n*64 + c] = fmaxf(o, 0.f);
  }
}

// ---------- DiffGroupNorm ----------
__global__ __launch_bounds__(256,4) void k_dgn_s(const float* __restrict__ x,
  const float* __restrict__ WT /*10x64*/, const float* __restrict__ b,
  float* __restrict__ s, int N)
{
  int n = blockIdx.x*256 + threadIdx.x;
  if (n >= N) return;
  float a[64];
  const float4* p = (const float4*)(x + (size_t)n*64);
  #pragma unroll
  for (int i=0;i<16;i++){ float4 v=p[i]; a[4*i]=v.x; a[4*i+1]=v.y; a[4*i+2]=v.z; a[4*i+3]=v.w; }
  float lg[10];
  #pragma unroll
  for (int g=0; g<10; g++){
    float acc = b[g];
    const float* w = WT + (size_t)g*64;
    #pragma unroll
    for (int k=0;k<64;k++) acc = fmaf(a[k], w[k], acc);
    lg[g] = acc;
  }
  float m = lg[0];
  #pragma unroll
  for (int g=1;g<10;g++) m = fmaxf(m, lg[g]);
  float e[10], sum = 0.f;
  #pragma unroll
  for (int g=0;g<10;g++){ e[g] = __expf(lg[g]-m); sum += e[g]; }
  float inv = 1.f/sum;
  #pragma unroll
  for (int g=0;g<10;g++) s[(size_t)n*10+g] = e[g]*inv;
}

__global__ __launch_bounds__(640) void k_dgn_stats(const float* __restrict__ s,
  const float* __restrict__ x, float* cs, float* cs2, int N)
{
  int g = threadIdx.x >> 6, f = threadIdx.x & 63;
  int per = (N + gridDim.x - 1) / gridDim.x;
  int n0 = blockIdx.x * per;
  int n1 = min(N, n0 + per);
  float a = 0.f, a2 = 0.f;
  for (int n = n0; n < n1; n++){
    float y = s[(size_t)n*10+g] * x[(size_t)n*64+f];
    a += y; a2 += y*y;
  }
  atomicAdd(&cs [g*64+f], a);
  atomicAdd(&cs2[g*64+f], a2);
}

__global__ void k_dgn_final(const float* cs, const float* cs2,
  const float* __restrict__ bw, const float* __restrict__ bb,
  float* scale, float* shiftsum, int N)
{
  __shared__ float sh[640];
  int i = threadIdx.x;
  float invN = 1.f / (float)N;
  float mean = cs[i]*invN;
  float var  = cs2[i]*invN - mean*mean;
  float sc = bw[i] / sqrtf(var + 1e-5f);
  scale[i] = sc;
  sh[i] = bb[i] - mean*sc;
  __syncthreads();
  if (i < 64){
    float t = 0.f;
    #pragma unroll
    for (int g=0;g<10;g++) t += sh[g*64+i];
    shiftsum[i] = t;
  }
}

__global__ __launch_bounds__(256) void k_dgn_apply(float* x,
  const float* __restrict__ s, const float* __restrict__ scale,
  const float* __restrict__ shiftsum, int N)
{
  int idx = blockIdx.x*256 + threadIdx.x;
  if (idx >= N*64) return;
  int n = idx >> 6, f = idx & 63;
  float ss = 0.f;
  #pragma unroll
  for (int g=0; g<10; g++) ss = fmaf(s[(size_t)n*10+g], scale[g*64+f], ss);
  float xvv = x[idx];
  x[idx] = xvv + 0.01f*(xvv*ss + shiftsum[f]);
}

// ---------- readout: gout[g] = relu(sum of x rows in [goffs[g], goffs[g+1})) ----------
__global__ __launch_bounds__(256) void k_readout(const int* __restrict__ goffs,
  const float* __restrict__ x, float* __restrict__ gout)
{
  int g = blockIdx.x;
  int lane = threadIdx.x & 63, wv = threadIdx.x >> 6;
  __shared__ float accs[4][64];
  int n0 = goffs[g], n1 = goffs[g+1];
  float a = 0.f;
  for (int n = n0 + wv; n < n1; n += 4) a += x[(size_t)n*64 + lane];
  accs[wv][lane] = a;
  __syncthreads();
  if (wv==0){
    float s = accs[0][lane]+accs[1][lane]+accs[2][lane]+accs[3][lane];
    gout[(size_t)g*64 + lane] = fmaxf(s, 0.f);
  }
}

__global__ __launch_bounds__(256) void k_head(const float* __restrict__ y,
  const float* __restrict__ w, const float* __restrict__ b,
  float* __restrict__ out, int N)
{
  int n = blockIdx.x*256 + threadIdx.x;
  if (n >= N) return;
  float acc = b[0];
  const float4* p = (const float4*)(y + (size_t)n*64);
  #pragma unroll
  for (int i=0;i<16;i++){
    float4 v = p[i];
    acc = fmaf(v.x, w[4*i+0], acc);
    acc = fmaf(v.y, w[4*i+1], acc);
    acc = fmaf(v.z, w[4*i+2], acc);
    acc = fmaf(v.w, w[4*i+3], acc);
  }
  out[n] = acc;
}

// ---------- host ----------
extern "C" void kernel_launch(void* const* d_in, const int* in_sizes, int n_in,
                              void* d_out, int out_size, void* d_ws, size_t ws_size,
                              hipStream_t stream) {
  (void)in_sizes; (void)n_in; (void)out_size; (void)ws_size;

  // ----- workspace layout -----
  char* base = (char*)d_ws; size_t off = 0;
  auto A = [&](size_t bytes)->void*{ void* p = base + off; off += (bytes + 255) & ~(size_t)255; return p; };
  unsigned short* e_emb = (unsigned short*)A((size_t)N_EDGES*64*2);
  float* xbuf   = (float*)A((size_t)N_NODES*64*4);
  float* xl     = (float*)A((size_t)N_NODES*64*4);
  float* xr     = (float*)A((size_t)N_NODES*64*4);
  float* hbuf   = (float*)A((size_t)N_NODES*64*4);
  float* logits = (float*)A((size_t)N_EDGES*4);
  int* deg      = (int*)A((size_t)N_NODES*4);
  int* offs     = (int*)A((size_t)(N_NODES+1)*4);
  int* cursor   = (int*)A((size_t)N_NODES*4);
  int* csr_src  = (int*)A((size_t)N_EDGES*4);
  int* csr_eid  = (int*)A((size_t)N_EDGES*4);
  int* goffs    = (int*)A((size_t)(N_GRAPHS+1)*4);
  float* sbuf   = (float*)A((size_t)N_NODES*10*4);
  float* gout   = (float*)A((size_t)N_GRAPHS*64*4);
  float* ybuf   = (float*)A((size_t)N_GRAPHS*64*4);
  float* ybuf2  = (float*)A((size_t)N_GRAPHS*64*4);
  float* colsum = (float*)A(2*640*4); float* colsumsq = colsum + 640;
  float* scale  = (float*)A((640+64)*4); float* shiftsum = scale + 640;
  float* wf     = (float*)A(60000*4);
  size_t wo = 0;
  auto W = [&](size_t n)->float*{ float* p = wf + wo; wo += n; return p; };

  float* pre_nWT = W(64*92);
  float* pre_eWT = W(64*50);
  float* WeT[2] = {W(4096), W(4096)};
  float* WlT[2] = {W(4096), W(4096)};
  float* WrT[2] = {W(4096), W(4096)};
  float* gnWT[2] = {W(640), W(640)};
  float* gWlT = W(4096);
  float* gWrT = W(4096);
  float* ggnWT = W(640);
  float* postWT[2] = {W(4096), W(4096)};

  const float* F[48];
  for (int i=0;i<41;i++) F[i] = (const float*)d_in[i];

  CvtArgs ca; ca.cnt = 0;
  auto addT = [&](const float* s, float* d, int r, int c){
    ca.e[ca.cnt].s=s; ca.e[ca.cnt].d=d; ca.e[ca.cnt].rows=r; ca.e[ca.cnt].cols=c; ca.cnt++; };

  addT(F[4],  pre_nWT, 92, 64);
  addT(F[6],  pre_eWT, 50, 64);
  for (int l=0;l<2;l++) addT(F[8]  + l*4096, WlT[l], 64, 64);
  for (int l=0;l<2;l++) addT(F[10] + l*4096, WrT[l], 64, 64);
  for (int l=0;l<2;l++) addT(F[12] + l*4096, WeT[l], 64, 64);
  for (int l=0;l<2;l++) addT(F[19] + l*640,  gnWT[l], 64, 10);
  addT(F[23], gWlT, 64, 64);
  addT(F[25], gWrT, 64, 64);
  addT(F[33], ggnWT, 64, 10);
  for (int l=0;l<2;l++) addT(F[37] + l*4096, postWT[l], 64, 64);

  const int* src   = (const int*)d_in[1];
  const int* dst   = src + N_EDGES;
  const int* batch = (const int*)d_in[3];

  const int NBn = (N_NODES + 255)/256;
  const int NBe = N_EDGES/256;
  const int NBg = (N_GRAPHS + 255)/256;
  const int NBw = (N_NODES*64)/256;      // wave-per-node grids

  k_convert<<<dim3(24, ca.cnt), 256, 0, stream>>>(ca);

  // CSR build (edge_index constant; rebuilt each call, no static state)
  hipMemsetAsync(deg, 0, (size_t)N_NODES*4, stream);
  k_deg<<<NBe,256,0,stream>>>(dst, deg);
  k_scan<<<1,1024,0,stream>>>(deg, offs, cursor);
  k_fill<<<NBe,256,0,stream>>>(src, dst, cursor, csr_src, csr_eid);
  k_goffs<<<NBn,256,0,stream>>>(batch, goffs);

  // x = relu(x_in @ pre_nW + pre_nb)
  k_linear64<92,1><<<NBn,256,0,stream>>>(F[0], pre_nWT, F[5], xbuf, N_NODES);

  for (int l=0; l<2; l++){
    k_edge_mlp<<<NBe,256,0,stream>>>(F[2], pre_eWT, F[7], WeT[l], e_emb);
    for (int t=0; t<2; t++){
      k_linear64<64,0><<<NBn,256,0,stream>>>(xbuf, WlT[l], F[9]  + l*64, xl, N_NODES);
      k_linear64<64,0><<<NBn,256,0,stream>>>(xbuf, WrT[l], F[11] + l*64, xr, N_NODES);
      k_gat_csr<<<NBw,256,0,stream>>>(offs, csr_src, csr_eid, xl, xr, e_emb,
                                      F[13] + l*64, F[14] + l*64, logits, hbuf);
      k_gru<<<NBn,256,0,stream>>>(hbuf, xbuf, F[15] + l*12288, F[16] + l*12288,
                                  F[17] + l*192, F[18] + l*192, N_NODES);
    }
    hipMemsetAsync(colsum, 0, 2*640*4, stream);
    k_dgn_s<<<NBn,256,0,stream>>>(xbuf, gnWT[l], F[20] + l*10, sbuf, N_NODES);
    k_dgn_stats<<<128,640,0,stream>>>(sbuf, xbuf, colsum, colsumsq, N_NODES);
    k_dgn_final<<<1,640,0,stream>>>(colsum, colsumsq, F[21] + l*640, F[22] + l*640, scale, shiftsum, N_NODES);
    k_dgn_apply<<<NBw,256,0,stream>>>(xbuf, sbuf, scale, shiftsum, N_NODES);
  }

  // readout
  k_readout<<<N_GRAPHS,256,0,stream>>>(goffs, xbuf, gout);

  // global attention: xl fixed across both timesteps
  k_linear64<64,0><<<NBn,256,0,stream>>>(xbuf, gWlT, F[24], xl, N_NODES);
  for (int t=0; t<2; t++){
    k_linear64<64,0><<<NBg,256,0,stream>>>(gout, gWrT, F[26], xr, N_GRAPHS);
    k_gat_graph<<<N_GRAPHS,256,0,stream>>>(goffs, xl, xr, F[27], F[28], logits, hbuf);
    k_gru<<<NBg,256,0,stream>>>(hbuf, gout, F[29], F[30], F[31], F[32], N_GRAPHS);
  }

  hipMemsetAsync(colsum, 0, 2*640*4, stream);
  k_dgn_s<<<NBg,256,0,stream>>>(gout, ggnWT, F[34], sbuf, N_GRAPHS);
  k_dgn_stats<<<8,640,0,stream>>>(sbuf, gout, colsum, colsumsq, N_GRAPHS);
  k_dgn_final<<<1,640,0,stream>>>(colsum, colsumsq, F[35], F[36], scale, shiftsum, N_GRAPHS);
  k_dgn_apply<<<(N_GRAPHS*64+255)/256,256,0,stream>>>(gout, sbuf, scale, shiftsum, N_GRAPHS);

  // post MLP + head
  k_linear64<64,1><<<NBg,256,0,stream>>>(gout, postWT[0], F[38],      ybuf,  N_GRAPHS);
  k_linear64<64,1><<<NBg,256,0,stream>>>(ybuf, postWT[1], F[38] + 64, ybuf2, N_GRAPHS);
  k_head<<<NBg,256,0,stream>>>(ybuf2, F[39], F[40], (float*)d_out, N_GRAPHS);
}